// Round 5
// baseline (441.940 us; speedup 1.0000x reference)
//
#include <hip/hip_runtime.h>
#include <math.h>

#define DIMC   1024
#define NTOK   2048
#define BATCH  2
#define HEADS  16
#define HDIM   64
#define HIDDEN 4096
#define MROWS  (BATCH*NTOK)                      /* 4096 token-rows */
#define QSZ    ((size_t)BATCH*HEADS*NTOK*HDIM)   /* 4194304 */
#define QSC    0.18033688f                       /* 64^-0.5 * log2(e), folded into q */

typedef unsigned short ushort_t;
typedef __attribute__((ext_vector_type(8))) short short8;
typedef __attribute__((ext_vector_type(4))) float f32x4;
typedef __attribute__((ext_vector_type(4))) unsigned short us4;

__device__ __forceinline__ ushort_t f2b(float f) {
  union { float f; unsigned int u; } cv; cv.f = f;
  unsigned int u = cv.u;
  unsigned int r = (u + 0x7fffu + ((u >> 16) & 1u)) >> 16;  // RNE
  return (ushort_t)r;
}

__device__ __forceinline__ float fexp2(float x) {
#if __has_builtin(__builtin_amdgcn_exp2f)
  return __builtin_amdgcn_exp2f(x);
#else
  return exp2f(x);
#endif
}

__device__ __forceinline__ void gl_lds16(const void* g, void* l) {
  __builtin_amdgcn_global_load_lds(
      (const __attribute__((address_space(1))) void*)g,
      (__attribute__((address_space(3))) void*)l, 16, 0, 0);
}

// ---------------- transpose x (B,C,N) fp32 -> xt (B,N,C) bf16 ----------------
__global__ __launch_bounds__(256) void k_transpose(const float* __restrict__ x,
                                                   ushort_t* __restrict__ xt) {
  __shared__ float t[32][33];
  int b  = blockIdx.z;
  int c0 = blockIdx.y * 32, n0 = blockIdx.x * 32;
  int tx = threadIdx.x, ty = threadIdx.y;  // (32,8)
#pragma unroll
  for (int l = 0; l < 4; l++)
    t[ty + l * 8][tx] = x[((size_t)(b * DIMC + c0 + ty + l * 8)) * NTOK + n0 + tx];
  __syncthreads();
#pragma unroll
  for (int l = 0; l < 4; l++)
    xt[((size_t)(b * NTOK + n0 + ty + l * 8)) * DIMC + c0 + tx] = f2b(t[tx][ty + l * 8]);
}

// ---------------- fp32 -> bf16 bulk convert (n divisible by 1024) ------------
__global__ __launch_bounds__(256) void k_f2b(const float* __restrict__ in,
                                             ushort_t* __restrict__ out) {
  int i = blockIdx.x * 256 + threadIdx.x;
  float4 v = ((const float4*)in)[i];
  us4 o; o.x = f2b(v.x); o.y = f2b(v.y); o.z = f2b(v.z); o.w = f2b(v.w);
  ((us4*)out)[i] = o;
}

// ---------------- bf16 MFMA GEMM: out = A(MxK) @ W(NcolsxK)^T + bias ---------
// 128x128 tile, 4 waves x 64x64, 16x16x32 MFMA. Single-barrier double-buffered
// staging (prefetch k+1 lands during compute of k). LDS chunk-XOR swizzle via
// the global source chunk (dest must stay lane-linear for global_load_lds):
// slot s of row r holds global chunk s^((r>>1)&3) -> fragment reads are 2-way
// bank aliasing (free, m136). XCD-aware 1D grid: bid&7 = XCD owns a col slab
// (W hot in its L2), cols iterate fastest so A row-slabs are reused
// back-to-back.
// EPI: 0 = qkv -> bf16 q(*QSC)/k/vT scatter, 1 = proj: h=2v fp32 + bf16,
//      2 = fc1+GELU bf16, 3 = fc2: residual + transposed fp32 store
template <int EPI, int NTX8, int KDIM>
__global__ __launch_bounds__(256) void k_gemm_bf16(const ushort_t* __restrict__ A,
                                                   const ushort_t* __restrict__ W,
                                                   const float* __restrict__ bias,
                                                   void* __restrict__ outv,
                                                   float* __restrict__ out2,
                                                   const float* __restrict__ extra) {
  __shared__ ushort_t As[2][128 * 32];
  __shared__ ushort_t Bs[2][128 * 32];
  const int tid = threadIdx.x;
  const int lane = tid & 63, wv = tid >> 6;
  const int bid = blockIdx.x;
  const int xcd = bid & 7, t = bid >> 3;
  const int row0 = (t / NTX8) * 128;
  const int col0 = (xcd * NTX8 + (t % NTX8)) * 128;
  const int wrow0 = (wv >> 1) * 64, wcol0 = (wv & 1) * 64;
  const int lm = lane & 15, lq = lane >> 4;
  const int srow = wv * 32 + (lane >> 2);              // + j*16
  const int gch = (lane & 3) ^ ((lane >> 3) & 3);      // swizzled global chunk
  const int sslot = (lane & 3) * 8;                    // lane-linear LDS slot
  const int sw8 = (lq ^ ((lm >> 1) & 3)) * 8;          // fragment read slot

  f32x4 acc[4][4];
#pragma unroll
  for (int i = 0; i < 4; i++)
#pragma unroll
    for (int j = 0; j < 4; j++) acc[i][j] = (f32x4){0.f, 0.f, 0.f, 0.f};

  auto stage = [&](int buf, int k0) {
#pragma unroll
    for (int j = 0; j < 2; j++) {
      int r = srow + j * 16;
      gl_lds16(A + (size_t)(row0 + r) * KDIM + k0 + gch * 8, &As[buf][r * 32 + sslot]);
      gl_lds16(W + (size_t)(col0 + r) * KDIM + k0 + gch * 8, &Bs[buf][r * 32 + sslot]);
    }
  };

  auto compute = [&](int buf) {
    short8 af[4], bf[4];
#pragma unroll
    for (int mi = 0; mi < 4; mi++)
      af[mi] = *(const short8*)&As[buf][(wrow0 + mi * 16 + lm) * 32 + sw8];
#pragma unroll
    for (int ni = 0; ni < 4; ni++)
      bf[ni] = *(const short8*)&Bs[buf][(wcol0 + ni * 16 + lm) * 32 + sw8];
#pragma unroll
    for (int mi = 0; mi < 4; mi++)
#pragma unroll
      for (int ni = 0; ni < 4; ni++)
        acc[mi][ni] = __builtin_amdgcn_mfma_f32_16x16x32_bf16(af[mi], bf[ni], acc[mi][ni], 0, 0, 0);
  };

  stage(0, 0);
#pragma unroll 1
  for (int kk = 0; kk < KDIM / 64; kk++) {
    const int k0 = kk * 64;
    __syncthreads();               // buf0 resident; prior reads of buf1 done
    if (k0 + 32 < KDIM) stage(1, k0 + 32);
    compute(0);
    __syncthreads();               // buf1 resident; reads of buf0 done
    if (k0 + 64 < KDIM) stage(0, k0 + 64);
    compute(1);
  }

#pragma unroll
  for (int mi = 0; mi < 4; mi++) {
#pragma unroll
    for (int ni = 0; ni < 4; ni++) {
#pragma unroll
      for (int r = 0; r < 4; r++) {
        const int row = row0 + wrow0 + mi * 16 + lq * 4 + r;
        const int col = col0 + wcol0 + ni * 16 + lm;
        float v = acc[mi][ni][r] + bias[col];
        if (EPI == 0) {  // qkv scatter: col = which*1024 + h*64 + d; bf16 outputs
          int which = col >> 10, rem = col & 1023, hh = rem >> 6, d = rem & 63;
          int bb = row >> 11, n = row & 2047;
          size_t bh = (size_t)(bb * HEADS + hh);
          ushort_t* o16 = (ushort_t*)outv;
          if (which == 0)
            o16[(bh * NTOK + n) * HDIM + d] = f2b(v * QSC);  // fold scale*log2e
          else if (which == 1)
            o16[QSZ + (bh * NTOK + n) * HDIM + d] = f2b(v);
          else
            o16[2 * QSZ + (bh * HDIM + d) * NTOK + n] = f2b(v);
        } else if (EPI == 1) {  // proj: h = out+out, store fp32 + bf16
          float hv = 2.f * v;
          out2[(size_t)row * DIMC + col] = hv;
          ((ushort_t*)outv)[(size_t)row * DIMC + col] = f2b(hv);
        } else if (EPI == 2) {  // fc1 + exact GELU, bf16 store
          float gv = 0.5f * v * (1.f + erff(v * 0.70710678118654752f));
          ((ushort_t*)outv)[(size_t)row * HIDDEN + col] = f2b(gv);
        } else {  // fc2: y = h + m, store (B,C,N) fp32
          float y = extra[(size_t)row * DIMC + col] + v;
          int bb = row >> 11, n = row & 2047;
          ((float*)outv)[((size_t)(bb * DIMC + col)) * NTOK + n] = y;
        }
      }
    }
  }
}

// ---------------- MFMA flash attention, fixed-max softmax_one ----------------
// out' = e^x/(1+Sum e^x) (max-sub dropped: ~2e-4 abs err; masked rows p=1
// exactly). Row-sum via ones-MFMA. q pre-scaled by SCALE*log2e. K/V double-
// buffered, one barrier per tile.
__global__ __launch_bounds__(256) void k_attn_mfma(const ushort_t* __restrict__ qkv,
                                                   const int* __restrict__ mask,
                                                   ushort_t* __restrict__ scram) {
  __shared__ ushort_t Kl[2][64 * 64];
  __shared__ ushort_t Vl[2][64 * 64];
  __shared__ ushort_t Pl[4 * 32 * 72];
  const int tid = threadIdx.x;
  const int lane = tid & 63, w = tid >> 6;
  const int lm = lane & 15, quad = lane >> 4;
  const int bh = blockIdx.y, b = bh >> 4, h = bh & 15;
  const int q0 = blockIdx.x * 128 + w * 32;
  const ushort_t* qg  = qkv + (size_t)bh * NTOK * HDIM;
  const ushort_t* kg  = qkv + QSZ + (size_t)bh * NTOK * HDIM;
  const ushort_t* vTg = qkv + 2 * QSZ + (size_t)bh * HDIM * NTOK;
  ushort_t* Pw = &Pl[w * 32 * 72];

  const short8 ones = {0x3F80, 0x3F80, 0x3F80, 0x3F80, 0x3F80, 0x3F80, 0x3F80, 0x3F80};

  // Q fragments (A-layout): m=lm, k=hf*32+quad*8+j  — register-resident
  short8 qf[2][2];
#pragma unroll
  for (int qs = 0; qs < 2; qs++)
#pragma unroll
    for (int hf = 0; hf < 2; hf++)
      qf[qs][hf] = *(const short8*)&qg[(size_t)(q0 + qs * 16 + lm) * HDIM + hf * 32 + quad * 8];

  bool mk[2][4];
#pragma unroll
  for (int qs = 0; qs < 2; qs++)
#pragma unroll
    for (int r = 0; r < 4; r++)
      mk[qs][r] = mask[(size_t)bh * NTOK + q0 + qs * 16 + quad * 4 + r] != 0;

  f32x4 O[2][4], La[2];
#pragma unroll
  for (int qs = 0; qs < 2; qs++) {
    La[qs] = (f32x4){0.f, 0.f, 0.f, 0.f};
#pragma unroll
    for (int r = 0; r < 4; r++) O[qs][r] = (f32x4){0.f, 0.f, 0.f, 0.f};
  }

  // staging indices: slot s (16B) -> row s>>3, stores global chunk (s&7)^(row&7)
  const int s0 = tid, s1 = tid + 256;
  const int r0 = s0 >> 3, g0 = (s0 & 7) ^ (r0 & 7);
  const int r1 = s1 >> 3, g1 = (s1 & 7) ^ (r1 & 7);

  // preload tile 0 into buffer 0
  gl_lds16(kg + (size_t)r0 * HDIM + g0 * 8, &Kl[0][s0 * 8]);
  gl_lds16(kg + (size_t)r1 * HDIM + g1 * 8, &Kl[0][s1 * 8]);
  gl_lds16(vTg + (size_t)r0 * NTOK + g0 * 8, &Vl[0][s0 * 8]);
  gl_lds16(vTg + (size_t)r1 * NTOK + g1 * 8, &Vl[0][s1 * 8]);

  for (int kt = 0; kt < NTOK; kt += 64) {
    const int cur = (kt >> 6) & 1, nxt = cur ^ 1;
    __syncthreads();  // drains vmcnt: tile kt resident; prior tile's reads done
    if (kt + 64 < NTOK) {  // async-stage next tile; lands before next barrier
      gl_lds16(kg + (size_t)(kt + 64 + r0) * HDIM + g0 * 8, &Kl[nxt][s0 * 8]);
      gl_lds16(kg + (size_t)(kt + 64 + r1) * HDIM + g1 * 8, &Kl[nxt][s1 * 8]);
      gl_lds16(vTg + (size_t)r0 * NTOK + kt + 64 + g0 * 8, &Vl[nxt][s0 * 8]);
      gl_lds16(vTg + (size_t)r1 * NTOK + kt + 64 + g1 * 8, &Vl[nxt][s1 * 8]);
    }

    // K fragments (B-layout): n=key=ksub*16+lm, k=hf*32+quad*8+j
    short8 kf[4][2];
#pragma unroll
    for (int ksub = 0; ksub < 4; ksub++)
#pragma unroll
      for (int hf = 0; hf < 2; hf++)
        kf[ksub][hf] = *(const short8*)&Kl[cur][(ksub * 16 + lm) * 64 + ((4 * hf + quad) ^ (lm & 7)) * 8];

#pragma unroll
    for (int qs = 0; qs < 2; qs++) {
      f32x4 S[4];
#pragma unroll
      for (int ksub = 0; ksub < 4; ksub++) {
        S[ksub] = (f32x4){0.f, 0.f, 0.f, 0.f};
        S[ksub] = __builtin_amdgcn_mfma_f32_16x16x32_bf16(qf[qs][0], kf[ksub][0], S[ksub], 0, 0, 0);
        S[ksub] = __builtin_amdgcn_mfma_f32_16x16x32_bf16(qf[qs][1], kf[ksub][1], S[ksub], 0, 0, 0);
      }
      // p = exp2(s) (q pre-scaled); masked rows: p = 1 exactly. Truncation cvt.
#pragma unroll
      for (int r = 0; r < 4; r++) {
        const int prow = qs * 16 + quad * 4 + r;
#pragma unroll
        for (int ksub = 0; ksub < 4; ksub++) {
          float p = mk[qs][r] ? fexp2(S[ksub][r]) : 1.0f;
          Pw[prow * 72 + ksub * 16 + lm] = (ushort_t)(__float_as_uint(p) >> 16);
        }
      }
    }
    __builtin_amdgcn_s_waitcnt(0xC07F);  // drain P ds_writes (same-wave RAW)

    // V fragments (B-layout): n=d=dsub*16+lm, k=key=hf*32+quad*8+j from vT LDS
    short8 vf[4][2];
#pragma unroll
    for (int dsub = 0; dsub < 4; dsub++)
#pragma unroll
      for (int hf = 0; hf < 2; hf++)
        vf[dsub][hf] = *(const short8*)&Vl[cur][(dsub * 16 + lm) * 64 + ((4 * hf + quad) ^ (lm & 7)) * 8];

#pragma unroll
    for (int qs = 0; qs < 2; qs++) {
      short8 pf[2];
#pragma unroll
      for (int hf = 0; hf < 2; hf++)
        pf[hf] = *(const short8*)&Pw[(qs * 16 + lm) * 72 + hf * 32 + quad * 8];
#pragma unroll
      for (int dsub = 0; dsub < 4; dsub++) {
        O[qs][dsub] = __builtin_amdgcn_mfma_f32_16x16x32_bf16(pf[0], vf[dsub][0], O[qs][dsub], 0, 0, 0);
        O[qs][dsub] = __builtin_amdgcn_mfma_f32_16x16x32_bf16(pf[1], vf[dsub][1], O[qs][dsub], 0, 0, 0);
      }
      La[qs] = __builtin_amdgcn_mfma_f32_16x16x32_bf16(pf[0], ones, La[qs], 0, 0, 0);
      La[qs] = __builtin_amdgcn_mfma_f32_16x16x32_bf16(pf[1], ones, La[qs], 0, 0, 0);
    }
  }

  // epilogue: /(1+l), scrambled merge (b,h,n,d) -> row d*32+h*2+(n>>10), col n&1023
#pragma unroll
  for (int qs = 0; qs < 2; qs++)
#pragma unroll
    for (int r = 0; r < 4; r++) {
      int n = q0 + qs * 16 + quad * 4 + r;
      float inv = 1.f / (1.f + La[qs][r]);
      int n1 = n >> 10, nn0 = n & 1023;
#pragma unroll
      for (int dsub = 0; dsub < 4; dsub++) {
        int d = dsub * 16 + lm;
        int np = d * 32 + h * 2 + n1;
        scram[((size_t)(b * NTOK + np)) * DIMC + nn0] = f2b(O[qs][dsub][r] * inv);
      }
    }
}

// ---------------- row LayerNorm over HIDDEN=4096, bf16 in-place --------------
__global__ __launch_bounds__(256) void k_ln(ushort_t* __restrict__ mid,
                                            const float* __restrict__ g,
                                            const float* __restrict__ bta) {
  const int row = blockIdx.x;
  ushort_t* p = mid + (size_t)row * HIDDEN;
  const int tid = threadIdx.x;
  float lv[16];
  float s = 0.f, s2 = 0.f;
#pragma unroll
  for (int i = 0; i < 4; i++) {
    us4 u = *(const us4*)&p[tid * 4 + i * 1024];
#pragma unroll
    for (int j = 0; j < 4; j++) {
      union { unsigned int u; float f; } cv;
      cv.u = ((unsigned int)((j == 0) ? u.x : (j == 1) ? u.y : (j == 2) ? u.z : u.w)) << 16;
      float xx = cv.f;
      lv[i * 4 + j] = xx;
      s += xx;
      s2 += xx * xx;
    }
  }
#pragma unroll
  for (int off = 32; off > 0; off >>= 1) {
    s += __shfl_down(s, off);
    s2 += __shfl_down(s2, off);
  }
  __shared__ float rs[4], rs2[4];
  if ((tid & 63) == 0) { rs[tid >> 6] = s; rs2[tid >> 6] = s2; }
  __syncthreads();
  float ts = rs[0] + rs[1] + rs[2] + rs[3];
  float ts2 = rs2[0] + rs2[1] + rs2[2] + rs2[3];
  float mu = ts * (1.f / HIDDEN);
  float var = ts2 * (1.f / HIDDEN) - mu * mu;
  float rstd = rsqrtf(var + 1e-5f);
#pragma unroll
  for (int i = 0; i < 4; i++) {
    us4 o;
#pragma unroll
    for (int j = 0; j < 4; j++) {
      int f = tid * 4 + i * 1024 + j;
      float y = (lv[i * 4 + j] - mu) * rstd * g[f] + bta[f];
      ushort_t ob = f2b(y);
      if (j == 0) o.x = ob; else if (j == 1) o.y = ob; else if (j == 2) o.z = ob; else o.w = ob;
    }
    *(us4*)&p[tid * 4 + i * 1024] = o;
  }
}

extern "C" void kernel_launch(void* const* d_in, const int* in_sizes, int n_in,
                              void* d_out, int out_size, void* d_ws, size_t ws_size,
                              hipStream_t stream) {
  const float* x      = (const float*)d_in[0];
  const int*   mask   = (const int*)d_in[1];
  const float* qkv_w  = (const float*)d_in[2];
  const float* qkv_b  = (const float*)d_in[3];
  const float* proj_w = (const float*)d_in[4];
  const float* proj_b = (const float*)d_in[5];
  const float* fc1_w  = (const float*)d_in[6];
  const float* fc1_b  = (const float*)d_in[7];
  const float* ln_g   = (const float*)d_in[8];
  const float* ln_b   = (const float*)d_in[9];
  const float* fc2_w  = (const float*)d_in[10];
  const float* fc2_b  = (const float*)d_in[11];

  char* w = (char*)d_ws;
  ushort_t* qkv16  = (ushort_t*)w;           w += 3 * QSZ * 2;                    // 25.2 MB
  float*    hbuf   = (float*)w;              w += (size_t)MROWS * DIMC * 4;       // 16.8 MB
  ushort_t* xtb    = (ushort_t*)w;           w += (size_t)MROWS * DIMC * 2;       //  8.4 MB
  ushort_t* scramb = (ushort_t*)w;           w += (size_t)MROWS * DIMC * 2;       //  8.4 MB
  ushort_t* hb     = (ushort_t*)w;           w += (size_t)MROWS * DIMC * 2;       //  8.4 MB
  ushort_t* mid    = (ushort_t*)w;           w += (size_t)MROWS * HIDDEN * 2;     // 33.6 MB
  ushort_t* wqkvb  = (ushort_t*)w;           w += (size_t)3 * DIMC * DIMC * 2;    //  6.3 MB
  ushort_t* wprojb = (ushort_t*)w;           w += (size_t)DIMC * DIMC * 2;        //  2.1 MB
  ushort_t* wfc1b  = (ushort_t*)w;           w += (size_t)HIDDEN * DIMC * 2;      //  8.4 MB
  ushort_t* wfc2b  = (ushort_t*)w;           w += (size_t)DIMC * HIDDEN * 2;      //  8.4 MB

  k_transpose<<<dim3(NTOK / 32, DIMC / 32, BATCH), dim3(32, 8), 0, stream>>>(x, xtb);
  k_f2b<<<dim3(3 * DIMC * DIMC / 1024), 256, 0, stream>>>(qkv_w, wqkvb);
  k_f2b<<<dim3(DIMC * DIMC / 1024), 256, 0, stream>>>(proj_w, wprojb);
  k_f2b<<<dim3(HIDDEN * DIMC / 1024), 256, 0, stream>>>(fc1_w, wfc1b);
  k_f2b<<<dim3(DIMC * HIDDEN / 1024), 256, 0, stream>>>(fc2_w, wfc2b);

  // grids are 1D: (ntx*nty) with ntx = cols/128 (divisible by 8), nty = 32
  k_gemm_bf16<0, 3, DIMC><<<dim3(24 * 32), 256, 0, stream>>>(
      xtb, wqkvb, qkv_b, qkv16, nullptr, nullptr);
  k_attn_mfma<<<dim3(NTOK / 128, BATCH * HEADS), 256, 0, stream>>>(
      qkv16, mask, scramb);
  k_gemm_bf16<1, 1, DIMC><<<dim3(8 * 32), 256, 0, stream>>>(
      scramb, wprojb, proj_b, hb, hbuf, nullptr);
  k_gemm_bf16<2, 4, DIMC><<<dim3(32 * 32), 256, 0, stream>>>(
      hb, wfc1b, fc1_b, mid, nullptr, nullptr);
  k_ln<<<dim3(MROWS), 256, 0, stream>>>(mid, ln_g, ln_b);
  k_gemm_bf16<3, 1, HIDDEN><<<dim3(8 * 32), 256, 0, stream>>>(
      mid, wfc2b, fc2_b, d_out, nullptr, hbuf);
}

// Round 6
// 391.850 us; speedup vs baseline: 1.1278x; 1.1278x over previous
//
#include <hip/hip_runtime.h>
#include <math.h>

#define DIMC   1024
#define NTOK   2048
#define BATCH  2
#define HEADS  16
#define HDIM   64
#define HIDDEN 4096
#define MROWS  (BATCH*NTOK)                      /* 4096 token-rows */
#define QSZ    ((size_t)BATCH*HEADS*NTOK*HDIM)   /* 4194304 */
#define QSC    0.18033688f                       /* 64^-0.5 * log2(e), folded into q */

typedef unsigned short ushort_t;
typedef __attribute__((ext_vector_type(8))) short short8;
typedef __attribute__((ext_vector_type(4))) float f32x4;
typedef __attribute__((ext_vector_type(4))) unsigned short us4;

__device__ __forceinline__ ushort_t f2b(float f) {
  union { float f; unsigned int u; } cv; cv.f = f;
  unsigned int u = cv.u;
  unsigned int r = (u + 0x7fffu + ((u >> 16) & 1u)) >> 16;  // RNE
  return (ushort_t)r;
}

__device__ __forceinline__ float b2f(ushort_t b) {
  union { unsigned int u; float f; } cv; cv.u = ((unsigned int)b) << 16;
  return cv.f;
}

__device__ __forceinline__ float fexp2(float x) {
#if __has_builtin(__builtin_amdgcn_exp2f)
  return __builtin_amdgcn_exp2f(x);
#else
  return exp2f(x);
#endif
}

__device__ __forceinline__ void gl_lds16(const void* g, void* l) {
  __builtin_amdgcn_global_load_lds(
      (const __attribute__((address_space(1))) void*)g,
      (__attribute__((address_space(3))) void*)l, 16, 0, 0);
}

// barrier that waits only LDS traffic (lgkmcnt(0)), NOT vmcnt — global loads
// land in private regs and need no cross-wave visibility. This is what lets
// the reg-staging prefetch stay in flight across the barrier (HIP
// __syncthreads' workgroup fence would drain vmcnt(0)).
__device__ __forceinline__ void lds_barrier() {
  __builtin_amdgcn_s_waitcnt(0xC07F);  // lgkmcnt(0), vmcnt/expcnt no-wait
  __builtin_amdgcn_s_barrier();
}

// ---------------- transpose x (B,C,N) fp32 -> xt (B,N,C) bf16 ----------------
__global__ __launch_bounds__(256) void k_transpose(const float* __restrict__ x,
                                                   ushort_t* __restrict__ xt) {
  __shared__ float t[32][33];
  int b  = blockIdx.z;
  int c0 = blockIdx.y * 32, n0 = blockIdx.x * 32;
  int tx = threadIdx.x, ty = threadIdx.y;  // (32,8)
#pragma unroll
  for (int l = 0; l < 4; l++)
    t[ty + l * 8][tx] = x[((size_t)(b * DIMC + c0 + ty + l * 8)) * NTOK + n0 + tx];
  __syncthreads();
#pragma unroll
  for (int l = 0; l < 4; l++)
    xt[((size_t)(b * NTOK + n0 + ty + l * 8)) * DIMC + c0 + tx] = f2b(t[tx][ty + l * 8]);
}

// ---------------- fused fp32 -> bf16 convert for all 4 weight tensors --------
__global__ __launch_bounds__(256) void k_f2b4(const float* __restrict__ w0,
                                              const float* __restrict__ w1,
                                              const float* __restrict__ w2,
                                              const float* __restrict__ w3,
                                              ushort_t* __restrict__ o0,
                                              ushort_t* __restrict__ o1,
                                              ushort_t* __restrict__ o2,
                                              ushort_t* __restrict__ o3) {
  int bid = blockIdx.x;
  const float* in; ushort_t* out; int base;
  if (bid < 3072)      { in = w0; out = o0; base = bid; }
  else if (bid < 4096) { in = w1; out = o1; base = bid - 3072; }
  else if (bid < 8192) { in = w2; out = o2; base = bid - 4096; }
  else                 { in = w3; out = o3; base = bid - 8192; }
  int i = base * 256 + threadIdx.x;
  float4 v = ((const float4*)in)[i];
  us4 o; o.x = f2b(v.x); o.y = f2b(v.y); o.z = f2b(v.z); o.w = f2b(v.w);
  ((us4*)out)[i] = o;
}

// ---------------- bf16 MFMA GEMM: out = A(MxK) @ W(NcolsxK)^T + bias ---------
// 128x128 tile, 4 waves x 64x64, 16x16x32 MFMA. Reg-staging pipeline:
// global->VGPR loads with distance-2 prefetch, ds_write one iter later
// (compiler emits vmcnt(N) before the ds_write, never at the barrier), raw
// lgkm-only barrier. XOR chunk swizzle (slot s of row r holds global chunk
// s^((r>>1)&3)) -> conflict-free staging writes and fragment reads.
// EPI: 0 = qkv -> bf16 q(*QSC)/k/vT scatter, 1 = proj: h=2v bf16,
//      2 = fc1 raw bf16 (GELU folded into LN), 3 = fc2: bf16 residual +
//      transposed fp32 store
template <int EPI, int NTX8, int KDIM>
__global__ __launch_bounds__(256) void k_gemm_bf16(const ushort_t* __restrict__ A,
                                                   const ushort_t* __restrict__ W,
                                                   const float* __restrict__ bias,
                                                   void* __restrict__ outv,
                                                   const ushort_t* __restrict__ extra) {
  __shared__ ushort_t As[2][128 * 32];
  __shared__ ushort_t Bs[2][128 * 32];
  const int tid = threadIdx.x;
  const int lane = tid & 63, wv = tid >> 6;
  const int bid = blockIdx.x;
  const int xcd = bid & 7, t = bid >> 3;
  const int row0 = (t / NTX8) * 128;
  const int col0 = (xcd * NTX8 + (t % NTX8)) * 128;
  const int wrow0 = (wv >> 1) * 64, wcol0 = (wv & 1) * 64;
  const int lm = lane & 15, lq = lane >> 4;
  const int srow = wv * 32 + (lane >> 2);              // + j*16
  const int gch = (lane & 3) ^ ((lane >> 3) & 3);      // swizzled global chunk
  const int sslot = (lane & 3) * 8;                    // lane-linear LDS slot
  const int sw8 = (lq ^ ((lm >> 1) & 3)) * 8;          // fragment read slot

  const ushort_t* Ab = A + (size_t)(row0 + srow) * KDIM + gch * 8;
  const ushort_t* Wb = W + (size_t)(col0 + srow) * KDIM + gch * 8;
  const size_t rstep = (size_t)16 * KDIM;

  short8 ga0[2], gb0[2], ga1[2], gb1[2];

  f32x4 acc[4][4];
#pragma unroll
  for (int i = 0; i < 4; i++)
#pragma unroll
    for (int j = 0; j < 4; j++) acc[i][j] = (f32x4){0.f, 0.f, 0.f, 0.f};

#define GLOAD(sl, k0) do {                                     \
    ga##sl[0] = *(const short8*)(Ab + (k0));                   \
    ga##sl[1] = *(const short8*)(Ab + rstep + (k0));           \
    gb##sl[0] = *(const short8*)(Wb + (k0));                   \
    gb##sl[1] = *(const short8*)(Wb + rstep + (k0));           \
  } while (0)
#define SWRITE(buf, sl) do {                                   \
    *(short8*)&As[buf][srow * 32 + sslot]        = ga##sl[0];  \
    *(short8*)&As[buf][(srow + 16) * 32 + sslot] = ga##sl[1];  \
    *(short8*)&Bs[buf][srow * 32 + sslot]        = gb##sl[0];  \
    *(short8*)&Bs[buf][(srow + 16) * 32 + sslot] = gb##sl[1];  \
  } while (0)

  auto compute = [&](int buf) {
    short8 af[4], bf[4];
#pragma unroll
    for (int mi = 0; mi < 4; mi++)
      af[mi] = *(const short8*)&As[buf][(wrow0 + mi * 16 + lm) * 32 + sw8];
#pragma unroll
    for (int ni = 0; ni < 4; ni++)
      bf[ni] = *(const short8*)&Bs[buf][(wcol0 + ni * 16 + lm) * 32 + sw8];
#pragma unroll
    for (int mi = 0; mi < 4; mi++)
#pragma unroll
      for (int ni = 0; ni < 4; ni++)
        acc[mi][ni] = __builtin_amdgcn_mfma_f32_16x16x32_bf16(af[mi], bf[ni], acc[mi][ni], 0, 0, 0);
  };

  constexpr int S = KDIM / 32;  // 32 or 128, always even
  GLOAD(0, 0);          // tile 0 -> slot0
  GLOAD(1, 32);         // tile 1 -> slot1
  SWRITE(0, 0);         // buf0 <- tile 0 (vmcnt wait on slot0 only)

#pragma unroll 1
  for (int kk = 0; kk < S; kk += 2) {
    lds_barrier();                               // buf0 (tile kk) visible
    if (kk + 2 < S) GLOAD(0, (kk + 2) * 32);     // prefetch tile kk+2
    SWRITE(1, 1);                                // buf1 <- tile kk+1
    compute(0);                                  // tile kk
    lds_barrier();                               // buf1 (tile kk+1) visible
    if (kk + 3 < S) GLOAD(1, (kk + 3) * 32);     // prefetch tile kk+3
    if (kk + 2 < S) SWRITE(0, 0);                // buf0 <- tile kk+2
    compute(1);                                  // tile kk+1
  }
#undef GLOAD
#undef SWRITE

#pragma unroll
  for (int mi = 0; mi < 4; mi++) {
#pragma unroll
    for (int ni = 0; ni < 4; ni++) {
#pragma unroll
      for (int r = 0; r < 4; r++) {
        const int row = row0 + wrow0 + mi * 16 + lq * 4 + r;
        const int col = col0 + wcol0 + ni * 16 + lm;
        float v = acc[mi][ni][r] + bias[col];
        if (EPI == 0) {  // qkv scatter: col = which*1024 + h*64 + d; bf16 outputs
          int which = col >> 10, rem = col & 1023, hh = rem >> 6, d = rem & 63;
          int bb = row >> 11, n = row & 2047;
          size_t bh = (size_t)(bb * HEADS + hh);
          ushort_t* o16 = (ushort_t*)outv;
          if (which == 0)
            o16[(bh * NTOK + n) * HDIM + d] = f2b(v * QSC);  // fold scale*log2e
          else if (which == 1)
            o16[QSZ + (bh * NTOK + n) * HDIM + d] = f2b(v);
          else
            o16[2 * QSZ + (bh * HDIM + d) * NTOK + n] = f2b(v);
        } else if (EPI == 1) {  // proj: h = out+out, bf16 store
          ((ushort_t*)outv)[(size_t)row * DIMC + col] = f2b(2.f * v);
        } else if (EPI == 2) {  // fc1 raw (GELU applied in LN kernel)
          ((ushort_t*)outv)[(size_t)row * HIDDEN + col] = f2b(v);
        } else {  // fc2: y = h + m, h from bf16 hb, store (B,C,N) fp32
          float y = b2f(extra[(size_t)row * DIMC + col]) + v;
          int bb = row >> 11, n = row & 2047;
          ((float*)outv)[((size_t)(bb * DIMC + col)) * NTOK + n] = y;
        }
      }
    }
  }
}

// ---------------- MFMA flash attention, fixed-max softmax_one ----------------
// out' = e^x/(1+Sum e^x) (max-sub dropped: ~2e-4 abs err; masked rows p=1
// exactly). Row-sum via ones-MFMA. q pre-scaled by SCALE*log2e. K/V double-
// buffered, one barrier per tile.
__global__ __launch_bounds__(256) void k_attn_mfma(const ushort_t* __restrict__ qkv,
                                                   const int* __restrict__ mask,
                                                   ushort_t* __restrict__ scram) {
  __shared__ ushort_t Kl[2][64 * 64];
  __shared__ ushort_t Vl[2][64 * 64];
  __shared__ ushort_t Pl[4 * 32 * 72];
  const int tid = threadIdx.x;
  const int lane = tid & 63, w = tid >> 6;
  const int lm = lane & 15, quad = lane >> 4;
  const int bh = blockIdx.y, b = bh >> 4, h = bh & 15;
  const int q0 = blockIdx.x * 128 + w * 32;
  const ushort_t* qg  = qkv + (size_t)bh * NTOK * HDIM;
  const ushort_t* kg  = qkv + QSZ + (size_t)bh * NTOK * HDIM;
  const ushort_t* vTg = qkv + 2 * QSZ + (size_t)bh * HDIM * NTOK;
  ushort_t* Pw = &Pl[w * 32 * 72];

  const short8 ones = {0x3F80, 0x3F80, 0x3F80, 0x3F80, 0x3F80, 0x3F80, 0x3F80, 0x3F80};

  // Q fragments (A-layout): m=lm, k=hf*32+quad*8+j  — register-resident
  short8 qf[2][2];
#pragma unroll
  for (int qs = 0; qs < 2; qs++)
#pragma unroll
    for (int hf = 0; hf < 2; hf++)
      qf[qs][hf] = *(const short8*)&qg[(size_t)(q0 + qs * 16 + lm) * HDIM + hf * 32 + quad * 8];

  bool mk[2][4];
#pragma unroll
  for (int qs = 0; qs < 2; qs++)
#pragma unroll
    for (int r = 0; r < 4; r++)
      mk[qs][r] = mask[(size_t)bh * NTOK + q0 + qs * 16 + quad * 4 + r] != 0;

  f32x4 O[2][4], La[2];
#pragma unroll
  for (int qs = 0; qs < 2; qs++) {
    La[qs] = (f32x4){0.f, 0.f, 0.f, 0.f};
#pragma unroll
    for (int r = 0; r < 4; r++) O[qs][r] = (f32x4){0.f, 0.f, 0.f, 0.f};
  }

  // staging indices: slot s (16B) -> row s>>3, stores global chunk (s&7)^(row&7)
  const int s0 = tid, s1 = tid + 256;
  const int r0 = s0 >> 3, g0 = (s0 & 7) ^ (r0 & 7);
  const int r1 = s1 >> 3, g1 = (s1 & 7) ^ (r1 & 7);

  // preload tile 0 into buffer 0
  gl_lds16(kg + (size_t)r0 * HDIM + g0 * 8, &Kl[0][s0 * 8]);
  gl_lds16(kg + (size_t)r1 * HDIM + g1 * 8, &Kl[0][s1 * 8]);
  gl_lds16(vTg + (size_t)r0 * NTOK + g0 * 8, &Vl[0][s0 * 8]);
  gl_lds16(vTg + (size_t)r1 * NTOK + g1 * 8, &Vl[0][s1 * 8]);

  for (int kt = 0; kt < NTOK; kt += 64) {
    const int cur = (kt >> 6) & 1, nxt = cur ^ 1;
    __syncthreads();  // drains vmcnt: tile kt resident; prior tile's reads done
    if (kt + 64 < NTOK) {  // async-stage next tile; lands before next barrier
      gl_lds16(kg + (size_t)(kt + 64 + r0) * HDIM + g0 * 8, &Kl[nxt][s0 * 8]);
      gl_lds16(kg + (size_t)(kt + 64 + r1) * HDIM + g1 * 8, &Kl[nxt][s1 * 8]);
      gl_lds16(vTg + (size_t)r0 * NTOK + kt + 64 + g0 * 8, &Vl[nxt][s0 * 8]);
      gl_lds16(vTg + (size_t)r1 * NTOK + kt + 64 + g1 * 8, &Vl[nxt][s1 * 8]);
    }

    // K fragments (B-layout): n=key=ksub*16+lm, k=hf*32+quad*8+j
    short8 kf[4][2];
#pragma unroll
    for (int ksub = 0; ksub < 4; ksub++)
#pragma unroll
      for (int hf = 0; hf < 2; hf++)
        kf[ksub][hf] = *(const short8*)&Kl[cur][(ksub * 16 + lm) * 64 + ((4 * hf + quad) ^ (lm & 7)) * 8];

#pragma unroll
    for (int qs = 0; qs < 2; qs++) {
      f32x4 S[4];
#pragma unroll
      for (int ksub = 0; ksub < 4; ksub++) {
        S[ksub] = (f32x4){0.f, 0.f, 0.f, 0.f};
        S[ksub] = __builtin_amdgcn_mfma_f32_16x16x32_bf16(qf[qs][0], kf[ksub][0], S[ksub], 0, 0, 0);
        S[ksub] = __builtin_amdgcn_mfma_f32_16x16x32_bf16(qf[qs][1], kf[ksub][1], S[ksub], 0, 0, 0);
      }
      // p = exp2(s) (q pre-scaled); masked rows: p = 1 exactly. Truncation cvt.
#pragma unroll
      for (int r = 0; r < 4; r++) {
        const int prow = qs * 16 + quad * 4 + r;
#pragma unroll
        for (int ksub = 0; ksub < 4; ksub++) {
          float p = mk[qs][r] ? fexp2(S[ksub][r]) : 1.0f;
          Pw[prow * 72 + ksub * 16 + lm] = (ushort_t)(__float_as_uint(p) >> 16);
        }
      }
    }
    __builtin_amdgcn_s_waitcnt(0xC07F);  // drain P ds_writes (same-wave RAW)

    // V fragments (B-layout): n=d=dsub*16+lm, k=key=hf*32+quad*8+j from vT LDS
    short8 vf[4][2];
#pragma unroll
    for (int dsub = 0; dsub < 4; dsub++)
#pragma unroll
      for (int hf = 0; hf < 2; hf++)
        vf[dsub][hf] = *(const short8*)&Vl[cur][(dsub * 16 + lm) * 64 + ((4 * hf + quad) ^ (lm & 7)) * 8];

#pragma unroll
    for (int qs = 0; qs < 2; qs++) {
      short8 pf[2];
#pragma unroll
      for (int hf = 0; hf < 2; hf++)
        pf[hf] = *(const short8*)&Pw[(qs * 16 + lm) * 72 + hf * 32 + quad * 8];
#pragma unroll
      for (int dsub = 0; dsub < 4; dsub++) {
        O[qs][dsub] = __builtin_amdgcn_mfma_f32_16x16x32_bf16(pf[0], vf[dsub][0], O[qs][dsub], 0, 0, 0);
        O[qs][dsub] = __builtin_amdgcn_mfma_f32_16x16x32_bf16(pf[1], vf[dsub][1], O[qs][dsub], 0, 0, 0);
      }
      La[qs] = __builtin_amdgcn_mfma_f32_16x16x32_bf16(pf[0], ones, La[qs], 0, 0, 0);
      La[qs] = __builtin_amdgcn_mfma_f32_16x16x32_bf16(pf[1], ones, La[qs], 0, 0, 0);
    }
  }

  // epilogue: /(1+l), scrambled merge (b,h,n,d) -> row d*32+h*2+(n>>10), col n&1023
#pragma unroll
  for (int qs = 0; qs < 2; qs++)
#pragma unroll
    for (int r = 0; r < 4; r++) {
      int n = q0 + qs * 16 + quad * 4 + r;
      float inv = 1.f / (1.f + La[qs][r]);
      int n1 = n >> 10, nn0 = n & 1023;
#pragma unroll
      for (int dsub = 0; dsub < 4; dsub++) {
        int d = dsub * 16 + lm;
        int np = d * 32 + h * 2 + n1;
        scram[((size_t)(b * NTOK + np)) * DIMC + nn0] = f2b(O[qs][dsub][r] * inv);
      }
    }
}

// ---------------- GELU (exact, erf) + row LayerNorm over HIDDEN=4096 ---------
// Input mid holds raw fc1 output (bf16); apply GELU on load, then LN, write
// bf16 in place. GELU's VALU cost hides under this kernel's memory traffic.
__global__ __launch_bounds__(256) void k_ln(ushort_t* __restrict__ mid,
                                            const float* __restrict__ g,
                                            const float* __restrict__ bta) {
  const int row = blockIdx.x;
  ushort_t* p = mid + (size_t)row * HIDDEN;
  const int tid = threadIdx.x;
  float lv[16];
  float s = 0.f, s2 = 0.f;
#pragma unroll
  for (int i = 0; i < 4; i++) {
    us4 u = *(const us4*)&p[tid * 4 + i * 1024];
#pragma unroll
    for (int j = 0; j < 4; j++) {
      float xx = b2f((j == 0) ? u.x : (j == 1) ? u.y : (j == 2) ? u.z : u.w);
      xx = 0.5f * xx * (1.f + erff(xx * 0.70710678118654752f));  // exact GELU
      lv[i * 4 + j] = xx;
      s += xx;
      s2 += xx * xx;
    }
  }
#pragma unroll
  for (int off = 32; off > 0; off >>= 1) {
    s += __shfl_down(s, off);
    s2 += __shfl_down(s2, off);
  }
  __shared__ float rs[4], rs2[4];
  if ((tid & 63) == 0) { rs[tid >> 6] = s; rs2[tid >> 6] = s2; }
  __syncthreads();
  float ts = rs[0] + rs[1] + rs[2] + rs[3];
  float ts2 = rs2[0] + rs2[1] + rs2[2] + rs2[3];
  float mu = ts * (1.f / HIDDEN);
  float var = ts2 * (1.f / HIDDEN) - mu * mu;
  float rstd = rsqrtf(var + 1e-5f);
#pragma unroll
  for (int i = 0; i < 4; i++) {
    us4 o;
#pragma unroll
    for (int j = 0; j < 4; j++) {
      int f = tid * 4 + i * 1024 + j;
      float y = (lv[i * 4 + j] - mu) * rstd * g[f] + bta[f];
      ushort_t ob = f2b(y);
      if (j == 0) o.x = ob; else if (j == 1) o.y = ob; else if (j == 2) o.z = ob; else o.w = ob;
    }
    *(us4*)&p[tid * 4 + i * 1024] = o;
  }
}

extern "C" void kernel_launch(void* const* d_in, const int* in_sizes, int n_in,
                              void* d_out, int out_size, void* d_ws, size_t ws_size,
                              hipStream_t stream) {
  const float* x      = (const float*)d_in[0];
  const int*   mask   = (const int*)d_in[1];
  const float* qkv_w  = (const float*)d_in[2];
  const float* qkv_b  = (const float*)d_in[3];
  const float* proj_w = (const float*)d_in[4];
  const float* proj_b = (const float*)d_in[5];
  const float* fc1_w  = (const float*)d_in[6];
  const float* fc1_b  = (const float*)d_in[7];
  const float* ln_g   = (const float*)d_in[8];
  const float* ln_b   = (const float*)d_in[9];
  const float* fc2_w  = (const float*)d_in[10];
  const float* fc2_b  = (const float*)d_in[11];

  char* w = (char*)d_ws;
  ushort_t* qkv16  = (ushort_t*)w;           w += 3 * QSZ * 2;                    // 25.2 MB
  ushort_t* xtb    = (ushort_t*)w;           w += (size_t)MROWS * DIMC * 2;       //  8.4 MB
  ushort_t* scramb = (ushort_t*)w;           w += (size_t)MROWS * DIMC * 2;       //  8.4 MB
  ushort_t* hb     = (ushort_t*)w;           w += (size_t)MROWS * DIMC * 2;       //  8.4 MB
  ushort_t* mid    = (ushort_t*)w;           w += (size_t)MROWS * HIDDEN * 2;     // 33.6 MB
  ushort_t* wqkvb  = (ushort_t*)w;           w += (size_t)3 * DIMC * DIMC * 2;    //  6.3 MB
  ushort_t* wprojb = (ushort_t*)w;           w += (size_t)DIMC * DIMC * 2;        //  2.1 MB
  ushort_t* wfc1b  = (ushort_t*)w;           w += (size_t)HIDDEN * DIMC * 2;      //  8.4 MB
  ushort_t* wfc2b  = (ushort_t*)w;           w += (size_t)DIMC * HIDDEN * 2;      //  8.4 MB

  k_transpose<<<dim3(NTOK / 32, DIMC / 32, BATCH), dim3(32, 8), 0, stream>>>(x, xtb);
  k_f2b4<<<dim3(12288), 256, 0, stream>>>(qkv_w, proj_w, fc1_w, fc2_w,
                                          wqkvb, wprojb, wfc1b, wfc2b);

  // grids are 1D: (ntx*nty) with ntx = cols/128 (divisible by 8), nty = 32
  k_gemm_bf16<0, 3, DIMC><<<dim3(24 * 32), 256, 0, stream>>>(
      xtb, wqkvb, qkv_b, qkv16, nullptr);
  k_attn_mfma<<<dim3(NTOK / 128, BATCH * HEADS), 256, 0, stream>>>(
      qkv16, mask, scramb);
  k_gemm_bf16<1, 1, DIMC><<<dim3(8 * 32), 256, 0, stream>>>(
      scramb, wprojb, proj_b, hb, nullptr);
  k_gemm_bf16<2, 4, DIMC><<<dim3(32 * 32), 256, 0, stream>>>(
      hb, wfc1b, fc1_b, mid, nullptr);
  k_ln<<<dim3(MROWS), 256, 0, stream>>>(mid, ln_g, ln_b);
  k_gemm_bf16<3, 1, HIDDEN><<<dim3(8 * 32), 256, 0, stream>>>(
      mid, wfc2b, fc2_b, d_out, hb);
}

// Round 7
// 389.689 us; speedup vs baseline: 1.1341x; 1.0055x over previous
//
#include <hip/hip_runtime.h>
#include <math.h>

#define DIMC   1024
#define NTOK   2048
#define BATCH  2
#define HEADS  16
#define HDIM   64
#define HIDDEN 4096
#define MROWS  (BATCH*NTOK)                      /* 4096 token-rows */
#define QSZ    ((size_t)BATCH*HEADS*NTOK*HDIM)   /* 4194304 */
#define QSC    0.18033688f                       /* 64^-0.5 * log2(e), folded into q */

typedef unsigned short ushort_t;
typedef __attribute__((ext_vector_type(8))) short short8;
typedef __attribute__((ext_vector_type(4))) float f32x4;
typedef __attribute__((ext_vector_type(4))) unsigned short us4;

__device__ __forceinline__ ushort_t f2b(float f) {
  union { float f; unsigned int u; } cv; cv.f = f;
  unsigned int u = cv.u;
  unsigned int r = (u + 0x7fffu + ((u >> 16) & 1u)) >> 16;  // RNE
  return (ushort_t)r;
}

__device__ __forceinline__ float b2f(ushort_t b) {
  union { unsigned int u; float f; } cv; cv.u = ((unsigned int)b) << 16;
  return cv.f;
}

__device__ __forceinline__ float fexp2(float x) {
#if __has_builtin(__builtin_amdgcn_exp2f)
  return __builtin_amdgcn_exp2f(x);
#else
  return exp2f(x);
#endif
}

__device__ __forceinline__ void gl_lds16(const void* g, void* l) {
  __builtin_amdgcn_global_load_lds(
      (const __attribute__((address_space(1))) void*)g,
      (__attribute__((address_space(3))) void*)l, 16, 0, 0);
}

// barrier that waits only LDS traffic (lgkmcnt(0)), NOT vmcnt — global loads
// land in private regs and need no cross-wave visibility; prefetches stay in
// flight across the barrier.
__device__ __forceinline__ void lds_barrier() {
  __builtin_amdgcn_s_waitcnt(0xC07F);  // lgkmcnt(0), vmcnt/expcnt no-wait
  __builtin_amdgcn_s_barrier();
}

// ---------------- transpose x (B,C,N) fp32 -> xt (B,N,C) bf16 ----------------
__global__ __launch_bounds__(256) void k_transpose(const float* __restrict__ x,
                                                   ushort_t* __restrict__ xt) {
  __shared__ float t[32][33];
  int b  = blockIdx.z;
  int c0 = blockIdx.y * 32, n0 = blockIdx.x * 32;
  int tx = threadIdx.x, ty = threadIdx.y;  // (32,8)
#pragma unroll
  for (int l = 0; l < 4; l++)
    t[ty + l * 8][tx] = x[((size_t)(b * DIMC + c0 + ty + l * 8)) * NTOK + n0 + tx];
  __syncthreads();
#pragma unroll
  for (int l = 0; l < 4; l++)
    xt[((size_t)(b * NTOK + n0 + ty + l * 8)) * DIMC + c0 + tx] = f2b(t[tx][ty + l * 8]);
}

// ---------------- fused fp32 -> bf16 convert for all 4 weight tensors --------
__global__ __launch_bounds__(256) void k_f2b4(const float* __restrict__ w0,
                                              const float* __restrict__ w1,
                                              const float* __restrict__ w2,
                                              const float* __restrict__ w3,
                                              ushort_t* __restrict__ o0,
                                              ushort_t* __restrict__ o1,
                                              ushort_t* __restrict__ o2,
                                              ushort_t* __restrict__ o3) {
  int bid = blockIdx.x;
  const float* in; ushort_t* out; int base;
  if (bid < 3072)      { in = w0; out = o0; base = bid; }
  else if (bid < 4096) { in = w1; out = o1; base = bid - 3072; }
  else if (bid < 8192) { in = w2; out = o2; base = bid - 4096; }
  else                 { in = w3; out = o3; base = bid - 8192; }
  int i = base * 256 + threadIdx.x;
  float4 v = ((const float4*)in)[i];
  us4 o; o.x = f2b(v.x); o.y = f2b(v.y); o.z = f2b(v.z); o.w = f2b(v.w);
  ((us4*)out)[i] = o;
}

// ---------------- bf16 MFMA GEMM: out = A(MxK) @ W(NcolsxK)^T + bias ---------
// 128x128 tile, 4 waves x 64x64, 16x16x32 MFMA. Reg-staging pipeline
// (distance-2 global prefetch, ds_write one iter later, lgkm-only barrier),
// XOR chunk swizzle -> conflict-free LDS. XCD-aware 1D grid on blockIdx.x.
// Split-K via blockIdx.y (kz): A/W advance kz*KLEN, partial written per kz.
// EPI: 0 = qkv -> bf16 q(*QSC)/k/vT scatter, 2 = fc1 raw bf16 (GELU in LN),
//      4 = raw fp32 partial (no bias) at outv + kz*MROWS*DIMC
template <int EPI, int NTX8, int KSTRIDE, int KLEN>
__global__ __launch_bounds__(256) void k_gemm_bf16(const ushort_t* __restrict__ A,
                                                   const ushort_t* __restrict__ W,
                                                   const float* __restrict__ bias,
                                                   void* __restrict__ outv) {
  __shared__ ushort_t As[2][128 * 32];
  __shared__ ushort_t Bs[2][128 * 32];
  const int tid = threadIdx.x;
  const int lane = tid & 63, wv = tid >> 6;
  const int bid = blockIdx.x, kz = blockIdx.y;
  const int xcd = bid & 7, t = bid >> 3;
  const int row0 = (t / NTX8) * 128;
  const int col0 = (xcd * NTX8 + (t % NTX8)) * 128;
  const int wrow0 = (wv >> 1) * 64, wcol0 = (wv & 1) * 64;
  const int lm = lane & 15, lq = lane >> 4;
  const int srow = wv * 32 + (lane >> 2);              // + j*16
  const int gch = (lane & 3) ^ ((lane >> 3) & 3);      // swizzled global chunk
  const int sslot = (lane & 3) * 8;                    // lane-linear LDS slot
  const int sw8 = (lq ^ ((lm >> 1) & 3)) * 8;          // fragment read slot

  const ushort_t* Ab = A + (size_t)(row0 + srow) * KSTRIDE + (size_t)kz * KLEN + gch * 8;
  const ushort_t* Wb = W + (size_t)(col0 + srow) * KSTRIDE + (size_t)kz * KLEN + gch * 8;
  const size_t rstep = (size_t)16 * KSTRIDE;

  short8 ga0[2], gb0[2], ga1[2], gb1[2];

  f32x4 acc[4][4];
#pragma unroll
  for (int i = 0; i < 4; i++)
#pragma unroll
    for (int j = 0; j < 4; j++) acc[i][j] = (f32x4){0.f, 0.f, 0.f, 0.f};

#define GLOAD(sl, k0) do {                                     \
    ga##sl[0] = *(const short8*)(Ab + (k0));                   \
    ga##sl[1] = *(const short8*)(Ab + rstep + (k0));           \
    gb##sl[0] = *(const short8*)(Wb + (k0));                   \
    gb##sl[1] = *(const short8*)(Wb + rstep + (k0));           \
  } while (0)
#define SWRITE(buf, sl) do {                                   \
    *(short8*)&As[buf][srow * 32 + sslot]        = ga##sl[0];  \
    *(short8*)&As[buf][(srow + 16) * 32 + sslot] = ga##sl[1];  \
    *(short8*)&Bs[buf][srow * 32 + sslot]        = gb##sl[0];  \
    *(short8*)&Bs[buf][(srow + 16) * 32 + sslot] = gb##sl[1];  \
  } while (0)

  auto compute = [&](int buf) {
    short8 af[4], bf[4];
#pragma unroll
    for (int mi = 0; mi < 4; mi++)
      af[mi] = *(const short8*)&As[buf][(wrow0 + mi * 16 + lm) * 32 + sw8];
#pragma unroll
    for (int ni = 0; ni < 4; ni++)
      bf[ni] = *(const short8*)&Bs[buf][(wcol0 + ni * 16 + lm) * 32 + sw8];
#pragma unroll
    for (int mi = 0; mi < 4; mi++)
#pragma unroll
      for (int ni = 0; ni < 4; ni++)
        acc[mi][ni] = __builtin_amdgcn_mfma_f32_16x16x32_bf16(af[mi], bf[ni], acc[mi][ni], 0, 0, 0);
  };

  constexpr int S = KLEN / 32;  // 16/32/64, always even
  GLOAD(0, 0);          // tile 0 -> slot0
  GLOAD(1, 32);         // tile 1 -> slot1
  SWRITE(0, 0);         // buf0 <- tile 0 (vmcnt wait on slot0 only)

#pragma unroll 1
  for (int kk = 0; kk < S; kk += 2) {
    lds_barrier();                               // buf0 (tile kk) visible
    if (kk + 2 < S) GLOAD(0, (kk + 2) * 32);     // prefetch tile kk+2
    SWRITE(1, 1);                                // buf1 <- tile kk+1
    compute(0);                                  // tile kk
    lds_barrier();                               // buf1 (tile kk+1) visible
    if (kk + 3 < S) GLOAD(1, (kk + 3) * 32);     // prefetch tile kk+3
    if (kk + 2 < S) SWRITE(0, 0);                // buf0 <- tile kk+2
    compute(1);                                  // tile kk+1
  }
#undef GLOAD
#undef SWRITE

#pragma unroll
  for (int mi = 0; mi < 4; mi++) {
#pragma unroll
    for (int ni = 0; ni < 4; ni++) {
#pragma unroll
      for (int r = 0; r < 4; r++) {
        const int row = row0 + wrow0 + mi * 16 + lq * 4 + r;
        const int col = col0 + wcol0 + ni * 16 + lm;
        float v = acc[mi][ni][r];
        if (EPI != 4) v += bias[col];
        if (EPI == 0) {  // qkv scatter: col = which*1024 + h*64 + d; bf16 outputs
          int which = col >> 10, rem = col & 1023, hh = rem >> 6, d = rem & 63;
          int bb = row >> 11, n = row & 2047;
          size_t bh = (size_t)(bb * HEADS + hh);
          ushort_t* o16 = (ushort_t*)outv;
          if (which == 0)
            o16[(bh * NTOK + n) * HDIM + d] = f2b(v * QSC);  // fold scale*log2e
          else if (which == 1)
            o16[QSZ + (bh * NTOK + n) * HDIM + d] = f2b(v);
          else
            o16[2 * QSZ + (bh * HDIM + d) * NTOK + n] = f2b(v);
        } else if (EPI == 2) {  // fc1 raw (GELU applied in LN kernel)
          ((ushort_t*)outv)[(size_t)row * HIDDEN + col] = f2b(v);
        } else {  // EPI==4: raw fp32 partial for split-K
          ((float*)outv)[(size_t)kz * MROWS * DIMC + (size_t)row * DIMC + col] = v;
        }
      }
    }
  }
}

// ---------------- combine proj partials: hb = bf16(2*(p0+p1+bias)) -----------
__global__ __launch_bounds__(256) void k_comb_proj(const float* __restrict__ p0,
                                                   const float* __restrict__ p1,
                                                   const float* __restrict__ bias,
                                                   ushort_t* __restrict__ hb) {
  int i = blockIdx.x * 256 + threadIdx.x;          // float4 index
  int colb = (i & 255) * 4;
  float4 a = ((const float4*)p0)[i];
  float4 b = ((const float4*)p1)[i];
  us4 o;
  o.x = f2b(2.f * (a.x + b.x + bias[colb + 0]));
  o.y = f2b(2.f * (a.y + b.y + bias[colb + 1]));
  o.z = f2b(2.f * (a.z + b.z + bias[colb + 2]));
  o.w = f2b(2.f * (a.w + b.w + bias[colb + 3]));
  ((us4*)hb)[i] = o;
}

// ------- combine fc2 partials + residual, transposed store to (B,C,N) --------
__global__ __launch_bounds__(256) void k_comb_fc2(const float* __restrict__ p0,
                                                  const float* __restrict__ p1,
                                                  const ushort_t* __restrict__ hb,
                                                  const float* __restrict__ bias,
                                                  float* __restrict__ out) {
  __shared__ float t[32][33];
  int b  = blockIdx.z;
  int c0 = blockIdx.y * 32, n0 = blockIdx.x * 32;
  int tx = threadIdx.x, ty = threadIdx.y;  // (32,8)
#pragma unroll
  for (int l = 0; l < 4; l++) {
    size_t idx = ((size_t)(b * NTOK + n0 + ty + l * 8)) * DIMC + c0 + tx;
    t[ty + l * 8][tx] = p0[idx] + p1[idx] + b2f(hb[idx]) + bias[c0 + tx];
  }
  __syncthreads();
#pragma unroll
  for (int l = 0; l < 4; l++)
    out[((size_t)(b * DIMC + c0 + ty + l * 8)) * NTOK + n0 + tx] = t[tx][ty + l * 8];
}

// ---------------- MFMA flash attention, fixed-max softmax_one ----------------
// out' = e^x/(1+Sum e^x) (max-sub dropped: ~2e-4 abs err; masked rows p=1
// exactly). Row-sum via ones-MFMA. q pre-scaled by SCALE*log2e. K/V double-
// buffered, one barrier per tile.
__global__ __launch_bounds__(256) void k_attn_mfma(const ushort_t* __restrict__ qkv,
                                                   const int* __restrict__ mask,
                                                   ushort_t* __restrict__ scram) {
  __shared__ ushort_t Kl[2][64 * 64];
  __shared__ ushort_t Vl[2][64 * 64];
  __shared__ ushort_t Pl[4 * 32 * 72];
  const int tid = threadIdx.x;
  const int lane = tid & 63, w = tid >> 6;
  const int lm = lane & 15, quad = lane >> 4;
  const int bh = blockIdx.y, b = bh >> 4, h = bh & 15;
  const int q0 = blockIdx.x * 128 + w * 32;
  const ushort_t* qg  = qkv + (size_t)bh * NTOK * HDIM;
  const ushort_t* kg  = qkv + QSZ + (size_t)bh * NTOK * HDIM;
  const ushort_t* vTg = qkv + 2 * QSZ + (size_t)bh * HDIM * NTOK;
  ushort_t* Pw = &Pl[w * 32 * 72];

  const short8 ones = {0x3F80, 0x3F80, 0x3F80, 0x3F80, 0x3F80, 0x3F80, 0x3F80, 0x3F80};

  // Q fragments (A-layout): m=lm, k=hf*32+quad*8+j  — register-resident
  short8 qf[2][2];
#pragma unroll
  for (int qs = 0; qs < 2; qs++)
#pragma unroll
    for (int hf = 0; hf < 2; hf++)
      qf[qs][hf] = *(const short8*)&qg[(size_t)(q0 + qs * 16 + lm) * HDIM + hf * 32 + quad * 8];

  bool mk[2][4];
#pragma unroll
  for (int qs = 0; qs < 2; qs++)
#pragma unroll
    for (int r = 0; r < 4; r++)
      mk[qs][r] = mask[(size_t)bh * NTOK + q0 + qs * 16 + quad * 4 + r] != 0;

  f32x4 O[2][4], La[2];
#pragma unroll
  for (int qs = 0; qs < 2; qs++) {
    La[qs] = (f32x4){0.f, 0.f, 0.f, 0.f};
#pragma unroll
    for (int r = 0; r < 4; r++) O[qs][r] = (f32x4){0.f, 0.f, 0.f, 0.f};
  }

  // staging indices: slot s (16B) -> row s>>3, stores global chunk (s&7)^(row&7)
  const int s0 = tid, s1 = tid + 256;
  const int r0 = s0 >> 3, g0 = (s0 & 7) ^ (r0 & 7);
  const int r1 = s1 >> 3, g1 = (s1 & 7) ^ (r1 & 7);

  // preload tile 0 into buffer 0
  gl_lds16(kg + (size_t)r0 * HDIM + g0 * 8, &Kl[0][s0 * 8]);
  gl_lds16(kg + (size_t)r1 * HDIM + g1 * 8, &Kl[0][s1 * 8]);
  gl_lds16(vTg + (size_t)r0 * NTOK + g0 * 8, &Vl[0][s0 * 8]);
  gl_lds16(vTg + (size_t)r1 * NTOK + g1 * 8, &Vl[0][s1 * 8]);

  for (int kt = 0; kt < NTOK; kt += 64) {
    const int cur = (kt >> 6) & 1, nxt = cur ^ 1;
    __syncthreads();  // drains vmcnt: tile kt resident; prior tile's reads done
    if (kt + 64 < NTOK) {  // async-stage next tile; lands before next barrier
      gl_lds16(kg + (size_t)(kt + 64 + r0) * HDIM + g0 * 8, &Kl[nxt][s0 * 8]);
      gl_lds16(kg + (size_t)(kt + 64 + r1) * HDIM + g1 * 8, &Kl[nxt][s1 * 8]);
      gl_lds16(vTg + (size_t)r0 * NTOK + kt + 64 + g0 * 8, &Vl[nxt][s0 * 8]);
      gl_lds16(vTg + (size_t)r1 * NTOK + kt + 64 + g1 * 8, &Vl[nxt][s1 * 8]);
    }

    // K fragments (B-layout): n=key=ksub*16+lm, k=hf*32+quad*8+j
    short8 kf[4][2];
#pragma unroll
    for (int ksub = 0; ksub < 4; ksub++)
#pragma unroll
      for (int hf = 0; hf < 2; hf++)
        kf[ksub][hf] = *(const short8*)&Kl[cur][(ksub * 16 + lm) * 64 + ((4 * hf + quad) ^ (lm & 7)) * 8];

#pragma unroll
    for (int qs = 0; qs < 2; qs++) {
      f32x4 S[4];
#pragma unroll
      for (int ksub = 0; ksub < 4; ksub++) {
        S[ksub] = (f32x4){0.f, 0.f, 0.f, 0.f};
        S[ksub] = __builtin_amdgcn_mfma_f32_16x16x32_bf16(qf[qs][0], kf[ksub][0], S[ksub], 0, 0, 0);
        S[ksub] = __builtin_amdgcn_mfma_f32_16x16x32_bf16(qf[qs][1], kf[ksub][1], S[ksub], 0, 0, 0);
      }
      // p = exp2(s) (q pre-scaled); masked rows: p = 1 exactly. Truncation cvt.
#pragma unroll
      for (int r = 0; r < 4; r++) {
        const int prow = qs * 16 + quad * 4 + r;
#pragma unroll
        for (int ksub = 0; ksub < 4; ksub++) {
          float p = mk[qs][r] ? fexp2(S[ksub][r]) : 1.0f;
          Pw[prow * 72 + ksub * 16 + lm] = (ushort_t)(__float_as_uint(p) >> 16);
        }
      }
    }
    __builtin_amdgcn_s_waitcnt(0xC07F);  // drain P ds_writes (same-wave RAW)

    // V fragments (B-layout): n=d=dsub*16+lm, k=key=hf*32+quad*8+j from vT LDS
    short8 vf[4][2];
#pragma unroll
    for (int dsub = 0; dsub < 4; dsub++)
#pragma unroll
      for (int hf = 0; hf < 2; hf++)
        vf[dsub][hf] = *(const short8*)&Vl[cur][(dsub * 16 + lm) * 64 + ((4 * hf + quad) ^ (lm & 7)) * 8];

#pragma unroll
    for (int qs = 0; qs < 2; qs++) {
      short8 pf[2];
#pragma unroll
      for (int hf = 0; hf < 2; hf++)
        pf[hf] = *(const short8*)&Pw[(qs * 16 + lm) * 72 + hf * 32 + quad * 8];
#pragma unroll
      for (int dsub = 0; dsub < 4; dsub++) {
        O[qs][dsub] = __builtin_amdgcn_mfma_f32_16x16x32_bf16(pf[0], vf[dsub][0], O[qs][dsub], 0, 0, 0);
        O[qs][dsub] = __builtin_amdgcn_mfma_f32_16x16x32_bf16(pf[1], vf[dsub][1], O[qs][dsub], 0, 0, 0);
      }
      La[qs] = __builtin_amdgcn_mfma_f32_16x16x32_bf16(pf[0], ones, La[qs], 0, 0, 0);
      La[qs] = __builtin_amdgcn_mfma_f32_16x16x32_bf16(pf[1], ones, La[qs], 0, 0, 0);
    }
  }

  // epilogue: /(1+l), scrambled merge (b,h,n,d) -> row d*32+h*2+(n>>10), col n&1023
#pragma unroll
  for (int qs = 0; qs < 2; qs++)
#pragma unroll
    for (int r = 0; r < 4; r++) {
      int n = q0 + qs * 16 + quad * 4 + r;
      float inv = 1.f / (1.f + La[qs][r]);
      int n1 = n >> 10, nn0 = n & 1023;
#pragma unroll
      for (int dsub = 0; dsub < 4; dsub++) {
        int d = dsub * 16 + lm;
        int np = d * 32 + h * 2 + n1;
        scram[((size_t)(b * NTOK + np)) * DIMC + nn0] = f2b(O[qs][dsub][r] * inv);
      }
    }
}

// ---------------- GELU (exact, erf) + row LayerNorm over HIDDEN=4096 ---------
__global__ __launch_bounds__(256) void k_ln(ushort_t* __restrict__ mid,
                                            const float* __restrict__ g,
                                            const float* __restrict__ bta) {
  const int row = blockIdx.x;
  ushort_t* p = mid + (size_t)row * HIDDEN;
  const int tid = threadIdx.x;
  float lv[16];
  float s = 0.f, s2 = 0.f;
#pragma unroll
  for (int i = 0; i < 4; i++) {
    us4 u = *(const us4*)&p[tid * 4 + i * 1024];
#pragma unroll
    for (int j = 0; j < 4; j++) {
      float xx = b2f((j == 0) ? u.x : (j == 1) ? u.y : (j == 2) ? u.z : u.w);
      xx = 0.5f * xx * (1.f + erff(xx * 0.70710678118654752f));  // exact GELU
      lv[i * 4 + j] = xx;
      s += xx;
      s2 += xx * xx;
    }
  }
#pragma unroll
  for (int off = 32; off > 0; off >>= 1) {
    s += __shfl_down(s, off);
    s2 += __shfl_down(s2, off);
  }
  __shared__ float rs[4], rs2[4];
  if ((tid & 63) == 0) { rs[tid >> 6] = s; rs2[tid >> 6] = s2; }
  __syncthreads();
  float ts = rs[0] + rs[1] + rs[2] + rs[3];
  float ts2 = rs2[0] + rs2[1] + rs2[2] + rs2[3];
  float mu = ts * (1.f / HIDDEN);
  float var = ts2 * (1.f / HIDDEN) - mu * mu;
  float rstd = rsqrtf(var + 1e-5f);
#pragma unroll
  for (int i = 0; i < 4; i++) {
    us4 o;
#pragma unroll
    for (int j = 0; j < 4; j++) {
      int f = tid * 4 + i * 1024 + j;
      float y = (lv[i * 4 + j] - mu) * rstd * g[f] + bta[f];
      ushort_t ob = f2b(y);
      if (j == 0) o.x = ob; else if (j == 1) o.y = ob; else if (j == 2) o.z = ob; else o.w = ob;
    }
    *(us4*)&p[tid * 4 + i * 1024] = o;
  }
}

extern "C" void kernel_launch(void* const* d_in, const int* in_sizes, int n_in,
                              void* d_out, int out_size, void* d_ws, size_t ws_size,
                              hipStream_t stream) {
  const float* x      = (const float*)d_in[0];
  const int*   mask   = (const int*)d_in[1];
  const float* qkv_w  = (const float*)d_in[2];
  const float* qkv_b  = (const float*)d_in[3];
  const float* proj_w = (const float*)d_in[4];
  const float* proj_b = (const float*)d_in[5];
  const float* fc1_w  = (const float*)d_in[6];
  const float* fc1_b  = (const float*)d_in[7];
  const float* ln_g   = (const float*)d_in[8];
  const float* ln_b   = (const float*)d_in[9];
  const float* fc2_w  = (const float*)d_in[10];
  const float* fc2_b  = (const float*)d_in[11];

  char* w = (char*)d_ws;
  ushort_t* qkv16  = (ushort_t*)w;           w += 3 * QSZ * 2;                    // 25.2 MB
  ushort_t* xtb    = (ushort_t*)w;           w += (size_t)MROWS * DIMC * 2;       //  8.4 MB
  ushort_t* scramb = (ushort_t*)w;           w += (size_t)MROWS * DIMC * 2;       //  8.4 MB
  ushort_t* hb     = (ushort_t*)w;           w += (size_t)MROWS * DIMC * 2;       //  8.4 MB
  ushort_t* mid    = (ushort_t*)w;           w += (size_t)MROWS * HIDDEN * 2;     // 33.6 MB
  ushort_t* wqkvb  = (ushort_t*)w;           w += (size_t)3 * DIMC * DIMC * 2;    //  6.3 MB
  ushort_t* wprojb = (ushort_t*)w;           w += (size_t)DIMC * DIMC * 2;        //  2.1 MB
  ushort_t* wfc1b  = (ushort_t*)w;           w += (size_t)HIDDEN * DIMC * 2;      //  8.4 MB
  ushort_t* wfc2b  = (ushort_t*)w;           w += (size_t)DIMC * HIDDEN * 2;      //  8.4 MB
  float*    pbuf   = (float*)w;              w += (size_t)2 * MROWS * DIMC * 4;   // 33.6 MB
  float*    pbuf1  = pbuf + (size_t)MROWS * DIMC;

  k_transpose<<<dim3(NTOK / 32, DIMC / 32, BATCH), dim3(32, 8), 0, stream>>>(x, xtb);
  k_f2b4<<<dim3(12288), 256, 0, stream>>>(qkv_w, proj_w, fc1_w, fc2_w,
                                          wqkvb, wprojb, wfc1b, wfc2b);

  // 1D grids: (ntx*nty) with ntx = cols/128 (divisible by 8), nty = rows/128
  k_gemm_bf16<0, 3, DIMC, DIMC><<<dim3(24 * 32), 256, 0, stream>>>(
      xtb, wqkvb, qkv_b, qkv16);
  k_attn_mfma<<<dim3(NTOK / 128, BATCH * HEADS), 256, 0, stream>>>(
      qkv16, mask, scramb);
  // proj: split-K=2 (K=1024 -> 2x512), raw partials, combine adds bias & x2
  k_gemm_bf16<4, 1, DIMC, 512><<<dim3(8 * 32, 2), 256, 0, stream>>>(
      scramb, wprojb, nullptr, pbuf);
  k_comb_proj<<<dim3(4096), 256, 0, stream>>>(pbuf, pbuf1, proj_b, hb);
  k_gemm_bf16<2, 4, DIMC, DIMC><<<dim3(32 * 32), 256, 0, stream>>>(
      hb, wfc1b, fc1_b, mid);
  k_ln<<<dim3(MROWS), 256, 0, stream>>>(mid, ln_g, ln_b);
  // fc2: split-K=2 (K=4096 -> 2x2048), combine adds bias+residual, transposes
  k_gemm_bf16<4, 1, HIDDEN, 2048><<<dim3(8 * 32, 2), 256, 0, stream>>>(
      mid, wfc2b, nullptr, pbuf);
  k_comb_fc2<<<dim3(NTOK / 32, DIMC / 32, BATCH), dim3(32, 8), 0, stream>>>(
      pbuf, pbuf1, hb, fc2_b, (float*)d_out);
}